// Round 1
// baseline (113.480 us; speedup 1.0000x reference)
//
#include <hip/hip_runtime.h>

// DelayAudio: out[b,c,t] =
//   PAD  if t >= len[b] + C            (highest precedence)
//   EOS  if t >= c + offset + len[b]
//   SOS  if t <  c + offset
//   audio[b,c, t - c - offset] otherwise
// plus second output: len[b] + C.
// offset = target ? 0 : 1.

#define C_CH 8
#define SOS_TOK 1024
#define EOS_TOK 1025
#define PAD_TOK 1026

// Each block: one (b,c) row x one 1024-element output chunk.
// Stage source window (1024 + 16 halo ints) via aligned int4 loads into LDS,
// emit aligned int4 stores. Shift (c+offset in [0,8]) resolved in LDS.
__global__ __launch_bounds__(256) void delay_audio_kernel(
    const int* __restrict__ audio,      // [B, C, T] int32
    const int* __restrict__ audio_len,  // [B] int32
    const int* __restrict__ target,     // scalar
    int* __restrict__ out,              // [B, C, Tout] ++ [B]
    int B, int T, int Tout)
{
    const int chunk = blockIdx.x;
    const int row   = blockIdx.y;           // b * C + c
    const int b     = row >> 3;
    const int c     = row & 7;
    const int tid   = threadIdx.x;

    const int offset = (target[0] != 0) ? 0 : 1;
    const int len    = audio_len[b];
    const int start  = c + offset;          // SOS below this t
    const int eos_at = start + len;         // EOS from here
    const int pad_at = len + C_CH;          // PAD from here (wins)

    const int t0 = chunk << 10;             // chunk * 1024
    const long long arow = (long long)row * T;
    const long long orow = (long long)row * Tout;

    // Source window: src = t - start, t in [t0, t0+1024) -> src in
    // [t0 - 8, t0 + 1023]. Stage [t0-12, t0+1028) = 1040 ints (260 int4s),
    // aligned (t0 % 4 == 0). Clamp loads in-bounds; clamped garbage only
    // lands at lds indices that token branches override.
    __shared__ __align__(16) int lds[1040];
    const int s0 = t0 - 12;
    {
        int s  = s0 + (tid << 2);
        int sc = min(max(s, 0), T - 4);
        *(int4*)(lds + (tid << 2)) = *(const int4*)(audio + arow + sc);
        if (tid < 4) {
            int i2 = 256 + tid;
            int s2 = s0 + (i2 << 2);
            int sc2 = min(max(s2, 0), T - 4);
            *(int4*)(lds + (i2 << 2)) = *(const int4*)(audio + arow + sc2);
        }
    }
    __syncthreads();

    const int t = t0 + (tid << 2);
    if (t < Tout) {                          // Tout % 4 == 0 -> full int4 ok
        const int base = (tid << 2) + 12 - start;  // lds index of src for j=0
        int v[4];
#pragma unroll
        for (int j = 0; j < 4; ++j) {
            int pos = t + j;
            int g = lds[base + j];
            if (pos < start)   g = SOS_TOK;
            if (pos >= eos_at) g = EOS_TOK;
            if (pos >= pad_at) g = PAD_TOK;  // last write wins = precedence
            v[j] = g;
        }
        int4 r; r.x = v[0]; r.y = v[1]; r.z = v[2]; r.w = v[3];
        *(int4*)(out + orow + t) = r;
    }

    // Second output: audio_len + C, appended after the big tensor.
    if (blockIdx.x == 0 && blockIdx.y == 0 && tid < B) {
        out[(long long)B * C_CH * Tout + tid] = audio_len[tid] + C_CH;
    }
}

extern "C" void kernel_launch(void* const* d_in, const int* in_sizes, int n_in,
                              void* d_out, int out_size, void* d_ws, size_t ws_size,
                              hipStream_t stream) {
    const int* audio     = (const int*)d_in[0];
    const int* audio_len = (const int*)d_in[1];
    const int* target    = (const int*)d_in[2];
    int* out = (int*)d_out;

    const int B = in_sizes[1];                       // 64
    const int T = in_sizes[0] / (B * C_CH);          // 32768
    const int Tout = T + C_CH;                       // 32776

    const int chunks = (Tout + 1023) / 1024;         // 33
    dim3 grid(chunks, B * C_CH);                     // 33 x 512
    delay_audio_kernel<<<grid, 256, 0, stream>>>(
        audio, audio_len, target, out, B, T, Tout);
}

// Round 3
// 110.640 us; speedup vs baseline: 1.0257x; 1.0257x over previous
//
#include <hip/hip_runtime.h>

// DelayAudio: out[b,c,t] =
//   PAD  if t >= len[b] + C            (highest precedence)
//   EOS  if t >= c + offset + len[b]
//   SOS  if t <  c + offset
//   audio[b,c, t - c - offset] otherwise
// plus second output: len[b] + C.   offset = target ? 0 : 1.
//
// Key fact: shift s = c+offset is BLOCK-UNIFORM, so the gather is a uniform
// word rotation: out word W needs input words (W-qw) and (W-qw+1) only,
// combined by uniform rotation d = (4 - s%4) % 4. No LDS, no barrier.
// Both loads are aligned + coalesced; the second overlaps the first by 12 B
// and is served by L1/L2 (HBM fetch stays ~1x). Clamped out-of-range word
// loads only feed elements that the token branches override (proof: element
// j of word W reads src = 4W + j - s; clamping fires only when that src is
// < 0 (SOS region) or >= T (EOS/PAD region)).

#define C_CH 8
#define SOS_TOK 1024
#define EOS_TOK 1025
#define PAD_TOK 1026

typedef int iv4 __attribute__((ext_vector_type(4)));  // native vector type:
// __builtin_nontemporal_store rejects HIP's int4 class; ext_vector works.

__global__ __launch_bounds__(256) void delay_audio_kernel(
    const int* __restrict__ audio,      // [B, C, T] int32
    const int* __restrict__ audio_len,  // [B] int32
    const int* __restrict__ target,     // scalar
    int* __restrict__ out,              // [B, C, Tout] ++ [B]
    int B, int T, int Tout)
{
    const int row = blockIdx.y;          // b * C + c
    const int b   = row >> 3;
    const int c   = row & 7;
    const int tid = threadIdx.x;

    const int offset = (target[0] != 0) ? 0 : 1;
    const int s      = c + offset;       // shift, uniform per block, 0..8
    const int len    = audio_len[b];
    const int eos_at = s + len;
    const int pad_at = len + C_CH;

    const int TW    = T >> 2;            // input row length in int4 words
    const int ToutW = Tout >> 2;         // output row length in int4 words

    const int qw = (s + 3) >> 2;         // word offset
    const int d  = (4 - (s & 3)) & 3;    // uniform intra-word rotation

    const iv4* aw = (const iv4*)audio + (long long)row * TW;
    iv4*       ow = (iv4*)out + (long long)row * ToutW;

    const int baseW = blockIdx.x << 9;   // 512 output words per block

#pragma unroll
    for (int h = 0; h < 2; ++h) {
        const int W = baseW + (h << 8) + tid;   // coalesced within each half
        if (W >= ToutW) continue;
        const int wa  = W - qw;
        const int wai = min(max(wa, 0),     TW - 1);
        const int wbi = min(max(wa + 1, 0), TW - 1);
        const iv4 A  = aw[wai];
        const iv4 Bv = aw[wbi];

        iv4 g;                                   // uniform branch (s uniform)
        switch (d) {
            case 0:  g = A; break;
            case 1:  g = (iv4){A.y, A.z, A.w, Bv.x}; break;
            case 2:  g = (iv4){A.z, A.w, Bv.x, Bv.y}; break;
            default: g = (iv4){A.w, Bv.x, Bv.y, Bv.z}; break;
        }

        const int t = W << 2;
#pragma unroll
        for (int j = 0; j < 4; ++j) {
            const int pos = t + j;
            if (pos < s)       g[j] = SOS_TOK;
            if (pos >= eos_at) g[j] = EOS_TOK;
            if (pos >= pad_at) g[j] = PAD_TOK;   // last write wins = precedence
        }
        __builtin_nontemporal_store(g, &ow[W]);  // write-once, no reuse
    }

    // Second output: audio_len + C, appended after the big tensor.
    if (blockIdx.x == 0 && blockIdx.y == 0 && tid < B) {
        out[(long long)B * C_CH * Tout + tid] = audio_len[tid] + C_CH;
    }
}

extern "C" void kernel_launch(void* const* d_in, const int* in_sizes, int n_in,
                              void* d_out, int out_size, void* d_ws, size_t ws_size,
                              hipStream_t stream) {
    const int* audio     = (const int*)d_in[0];
    const int* audio_len = (const int*)d_in[1];
    const int* target    = (const int*)d_in[2];
    int* out = (int*)d_out;

    const int B = in_sizes[1];                       // 64
    const int T = in_sizes[0] / (B * C_CH);          // 32768
    const int Tout = T + C_CH;                       // 32776

    const int ToutW  = Tout >> 2;                    // 8194
    const int chunks = (ToutW + 511) / 512;          // 17
    dim3 grid(chunks, B * C_CH);                     // 17 x 512
    delay_audio_kernel<<<grid, 256, 0, stream>>>(
        audio, audio_len, target, out, B, T, Tout);
}

// Round 4
// 109.919 us; speedup vs baseline: 1.0324x; 1.0066x over previous
//
#include <hip/hip_runtime.h>

// DelayAudio: out[b,c,t] =
//   PAD  if t >= len[b] + C            (highest precedence)
//   EOS  if t >= c + offset + len[b]
//   SOS  if t <  c + offset
//   audio[b,c, t - c - offset] otherwise
// plus second output: len[b] + C.   offset = target ? 0 : 1.
//
// Shift s = c+offset is BLOCK-UNIFORM: the gather is a uniform word rotation.
// Out word W needs input words (W-qw) and (W-qw+1), combined by uniform
// rotation d = (4 - s%4) % 4. Word-granularity clamping is provably safe:
// a clamped (out-of-range) source WORD contributes only elements whose src
// is < 0 (SOS region) or >= T (EOS/PAD region), all overridden by tokens.
// (A misaligned single-load variant is NOT safe: clamping shifts valid
// elements within the word — wrong at the len==T row.)
//
// R4: 4 words/thread, all 8 loads issued before compute (MLP): the 134 MB
// working set fits in L3, so the kernel is latency/issue-bound, not HBM-bound.

#define C_CH 8
#define SOS_TOK 1024
#define EOS_TOK 1025
#define PAD_TOK 1026

typedef int iv4 __attribute__((ext_vector_type(4)));

__global__ __launch_bounds__(256) void delay_audio_kernel(
    const int* __restrict__ audio,      // [B, C, T] int32
    const int* __restrict__ audio_len,  // [B] int32
    const int* __restrict__ target,     // scalar
    int* __restrict__ out,              // [B, C, Tout] ++ [B]
    int B, int T, int Tout)
{
    const int row = blockIdx.y;          // b * C + c
    const int b   = row >> 3;
    const int c   = row & 7;
    const int tid = threadIdx.x;

    const int offset = (target[0] != 0) ? 0 : 1;
    const int s      = c + offset;       // shift, uniform per block, 0..8
    const int len    = audio_len[b];
    const int eos_at = s + len;
    const int pad_at = len + C_CH;

    const int TW    = T >> 2;            // input row length in int4 words
    const int ToutW = Tout >> 2;         // output row length in int4 words

    const int qw = (s + 3) >> 2;         // uniform word offset
    const int d  = (4 - (s & 3)) & 3;    // uniform intra-word rotation

    const iv4* aw = (const iv4*)audio + (long long)row * TW;
    iv4*       ow = (iv4*)out + (long long)row * ToutW;

    const int baseW = blockIdx.x << 10;  // 1024 output words per block

    // ---- phase 1: issue all loads (cluster for MLP) ----
    int W[4];
    iv4 A[4], Bv[4];
    bool act[4];
#pragma unroll
    for (int h = 0; h < 4; ++h) {
        W[h] = baseW + (h << 8) + tid;   // coalesced within each 256-word slab
        act[h] = (W[h] < ToutW);
        const int wa  = W[h] - qw;
        const int wai = min(max(wa, 0),     TW - 1);
        const int wbi = min(max(wa + 1, 0), TW - 1);
        if (act[h]) {
            A[h]  = aw[wai];
            Bv[h] = aw[wbi];
        }
    }

    // ---- phase 2: rotate, tokenize, store ----
#pragma unroll
    for (int h = 0; h < 4; ++h) {
        if (!act[h]) continue;
        iv4 g;                                   // uniform branch (s uniform)
        switch (d) {
            case 0:  g = A[h]; break;
            case 1:  g = (iv4){A[h].y, A[h].z, A[h].w, Bv[h].x}; break;
            case 2:  g = (iv4){A[h].z, A[h].w, Bv[h].x, Bv[h].y}; break;
            default: g = (iv4){A[h].w, Bv[h].x, Bv[h].y, Bv[h].z}; break;
        }
        const int t = W[h] << 2;
#pragma unroll
        for (int j = 0; j < 4; ++j) {
            const int pos = t + j;
            if (pos < s)       g[j] = SOS_TOK;
            if (pos >= eos_at) g[j] = EOS_TOK;
            if (pos >= pad_at) g[j] = PAD_TOK;   // last write wins = precedence
        }
        __builtin_nontemporal_store(g, &ow[W[h]]);
    }

    // Second output: audio_len + C, appended after the big tensor.
    if (blockIdx.x == 0 && blockIdx.y == 0 && tid < B) {
        out[(long long)B * C_CH * Tout + tid] = audio_len[tid] + C_CH;
    }
}

extern "C" void kernel_launch(void* const* d_in, const int* in_sizes, int n_in,
                              void* d_out, int out_size, void* d_ws, size_t ws_size,
                              hipStream_t stream) {
    const int* audio     = (const int*)d_in[0];
    const int* audio_len = (const int*)d_in[1];
    const int* target    = (const int*)d_in[2];
    int* out = (int*)d_out;

    const int B = in_sizes[1];                       // 64
    const int T = in_sizes[0] / (B * C_CH);          // 32768
    const int Tout = T + C_CH;                       // 32776

    const int ToutW  = Tout >> 2;                    // 8194
    const int chunks = (ToutW + 1023) / 1024;        // 9
    dim3 grid(chunks, B * C_CH);                     // 9 x 512
    delay_audio_kernel<<<grid, 256, 0, stream>>>(
        audio, audio_len, target, out, B, T, Tout);
}